// Round 9
// baseline (335.157 us; speedup 1.0000x reference)
//
#include <hip/hip_runtime.h>

#define N_NODES 50000
#define N_EDGES 800000
#define F 128
#define BN_EPS 1e-5f
#define SLOPE 0.22916666666666666f  // RReLU eval slope 11/48

#define NBKT 196          // coarse buckets (tgt>>8)
#define BKT_CAP 8192      // staging slots per bucket (mean 4096)
#define P1_CHUNK 4096
#define P1_EPB 16
#define P1_BLKS 196       // ceil(N_EDGES/P1_CHUNK)
#define CASTX_BLKS 6250   // N_NODES*F/4/256 (exact)
#define CASTW_BLKS 64
#define BKT_FINAL_CAP 8704   // >= cnt + 256*16 (pad-to-16 + min-16)
#define REC_CAP 1606016      // sum of strides: 800000 + 196*(16+4096)
#define N_TILES 3125      // N_NODES/16 (exact)
#define GG_GRID 1024

typedef __attribute__((ext_vector_type(8))) short bf16x8;
typedef __attribute__((ext_vector_type(4))) float f32x4;
typedef unsigned long long u64;

__device__ __forceinline__ float bf2f(ushort u) {
    union { uint i; float f; } v; v.i = (uint)u << 16; return v.f;
}
__device__ __forceinline__ ushort f2bf(float f) {
    union { float f; uint i; } v; v.f = f;
    uint r = v.i + 0x7fffu + ((v.i >> 16) & 1u);  // RNE
    return (ushort)(r >> 16);
}

// ============ s1p: sort pass 1 (bucket binning) + x/W bf16 casts, one launch ============
// staging record: bits[0:31] = src | bf16(w)<<16 ; bits[32:63] = tgt
__global__ __launch_bounds__(256) void s1p_k(const int* __restrict__ src,
        const int* __restrict__ tgt, const float* __restrict__ ew,
        int* __restrict__ bcur, u64* __restrict__ stg,
        const float* __restrict__ x, ushort* __restrict__ xb,
        const float* __restrict__ W1r, const float* __restrict__ W1t,
        const float* __restrict__ W2r, const float* __restrict__ W2t,
        ushort* __restrict__ wb) {
    const int b = blockIdx.x;
    if (b >= P1_BLKS) {
        if (b < P1_BLKS + CASTX_BLKS) {
            int i = (b - P1_BLKS) * 256 + threadIdx.x;
            float4 v = reinterpret_cast<const float4*>(x)[i];
            ushort4 o;
            o.x = f2bf(v.x); o.y = f2bf(v.y); o.z = f2bf(v.z); o.w = f2bf(v.w);
            reinterpret_cast<ushort4*>(xb)[i] = o;
        } else {
            int i = (b - P1_BLKS - CASTX_BLKS) * 256 + threadIdx.x;  // 16384 total
            int m = i >> 12;
            int j = i & 4095;
            const float* sp = (m == 0) ? W1r : (m == 1) ? W1t : (m == 2) ? W2r : W2t;
            float4 v = reinterpret_cast<const float4*>(sp)[j];
            ushort4 o;
            o.x = f2bf(v.x); o.y = f2bf(v.y); o.z = f2bf(v.z); o.w = f2bf(v.w);
            reinterpret_cast<ushort4*>(wb)[i] = o;
        }
        return;
    }
    // ---- sort pass 1 ----
    __shared__ uint cnt[256];
    __shared__ uint base[256];
    __shared__ uint lcur[256];
    __shared__ uint gbase[256];
    __shared__ u64 lrec[P1_CHUNK];  // 32 KB

    const int e0 = b * P1_CHUNK;
    const int nE = min(P1_CHUNK, N_EDGES - e0);
    cnt[threadIdx.x] = 0;
    __syncthreads();

    u64 myrec[P1_EPB];
    bool myok[P1_EPB];
#pragma unroll
    for (int k = 0; k < P1_EPB; ++k) {
        int idx = threadIdx.x + (k << 8);
        bool ok = idx < nE;
        myok[k] = ok;
        if (ok) {
            int e = e0 + idx;
            uint t = (uint)tgt[e];
            uint lo = (uint)(ushort)src[e] | ((uint)f2bf(ew[e]) << 16);
            myrec[k] = (u64)lo | ((u64)t << 32);
            atomicAdd(&cnt[t >> 8], 1u);
        }
    }
    __syncthreads();
    uint v = cnt[threadIdx.x];
    base[threadIdx.x] = v;
    __syncthreads();
    for (int o = 1; o < 256; o <<= 1) {
        uint t = (threadIdx.x >= (unsigned)o) ? base[threadIdx.x - o] : 0;
        __syncthreads();
        base[threadIdx.x] += t;
        __syncthreads();
    }
    uint excl = base[threadIdx.x] - v;
    base[threadIdx.x] = excl;
    lcur[threadIdx.x] = excl;
    if (threadIdx.x < NBKT && v > 0)
        gbase[threadIdx.x] = (uint)threadIdx.x * BKT_CAP +
                             (uint)atomicAdd(&bcur[threadIdx.x], (int)v);
    __syncthreads();
#pragma unroll
    for (int k = 0; k < P1_EPB; ++k) {
        if (myok[k]) {
            uint bb = (uint)(myrec[k] >> 40);
            uint slot = atomicAdd(&lcur[bb], 1u);
            lrec[slot] = myrec[k];
        }
    }
    __syncthreads();
    for (int s = threadIdx.x; s < nE; s += 256) {
        u64 r = lrec[s];
        uint bb = (uint)(r >> 40);
        stg[gbase[bb] + ((uint)s - base[bb])] = r;
    }
}

// ============ sort pass 2: per bucket -> final recs, src-sorted per node, via LDS ====
__global__ __launch_bounds__(256) void sort2_k(const int* __restrict__ bcur,
        const u64* __restrict__ stg, uint* __restrict__ recs, int2* __restrict__ rng) {
    __shared__ int lcnt[256];
    __shared__ int loff[256];
    __shared__ int lcur[256];
    __shared__ int sc[256];
    __shared__ int fbase_s;
    __shared__ uint lrec[BKT_FINAL_CAP];  // 34 KB
    const int b = blockIdx.x;
    const int tid = threadIdx.x;

    // redundant per-block scan of bucket strides -> this bucket's final base
    int cnt_t = (tid < NBKT) ? bcur[tid] : 0;
    int stride_t = (tid < NBKT) ? (((cnt_t + 15) & ~15) + 4096) : 0;
    sc[tid] = stride_t;
    lcnt[tid] = 0;
    __syncthreads();
    for (int o = 1; o < 256; o <<= 1) {
        int t = (tid >= o) ? sc[tid - o] : 0;
        __syncthreads();
        sc[tid] += t;
        __syncthreads();
    }
    if (tid == b) fbase_s = sc[tid] - stride_t;  // exclusive
    __syncthreads();
    const int fbase = fbase_s;
    const int cnt = bcur[b];
    const u64* sb = stg + (size_t)b * BKT_CAP;

    // per-node counts
    for (int i = tid; i < cnt; i += 256)
        atomicAdd(&lcnt[(int)(sb[i] >> 32) & 255], 1);
    __syncthreads();
    const int node = b * 256 + tid;
    int myc = lcnt[tid];
    int myp = (myc + 15) & ~15;          // pad to x16
    if (myp == 0) myp = 16;              // min 16 (uniform main gather loop)
    if (node >= N_NODES) myp = 0;
    sc[tid] = myp;
    __syncthreads();
    for (int o = 1; o < 256; o <<= 1) {
        int t = (tid >= o) ? sc[tid - o] : 0;
        __syncthreads();
        sc[tid] += t;
        __syncthreads();
    }
    const int myoff = sc[tid] - myp;     // exclusive local offset
    const int ptot = sc[255];            // total padded slots this bucket
    loff[tid] = myoff;
    lcur[tid] = myoff;
    if (node < N_NODES) rng[node] = make_int2(fbase + myoff, fbase + myoff + myp);
    // zero-fill (filler records are exact no-ops: src=0, w=+0)
    for (int i = tid; i < ptot; i += 256) lrec[i] = 0;
    __syncthreads();
    // place records (unordered within node)
    for (int i = tid; i < cnt; i += 256) {
        u64 r = sb[i];
        int n = (int)(r >> 32) & 255;
        int p = atomicAdd(&lcur[n], 1);
        lrec[p] = (uint)r;
    }
    __syncthreads();
    // per-thread insertion sort of own node's records by src (low 16 bits)
    {
        int s0_ = loff[tid];
        for (int i = 1; i < myc; ++i) {
            uint key = lrec[s0_ + i];
            ushort ks = (ushort)key;
            int j = i - 1;
            while (j >= 0 && (ushort)lrec[s0_ + j] > ks) {
                lrec[s0_ + j + 1] = lrec[s0_ + j];
                --j;
            }
            lrec[s0_ + j + 1] = key;
        }
    }
    __syncthreads();
    // coalesced dump
    for (int i = tid; i < ptot; i += 256) recs[fbase + i] = lrec[i];
}

// ============ fused gather + dual MFMA GEMM (+BN stats for layer 1) ============
// grid-stride tiles; wave w owns nodes w*4..w*4+3; gather interleaves record-index k
// across the 4 nodes (src-sorted records => lockstep sweep of featb => L2 locality).
__global__ __launch_bounds__(256) void gg_k(const ushort* __restrict__ featb,
        const int2* __restrict__ rng, const uint* __restrict__ recs,
        const ushort* __restrict__ Wr, const ushort* __restrict__ Wt,
        const float* __restrict__ bias, float* __restrict__ out,
        ushort* __restrict__ outh, float* __restrict__ S, float* __restrict__ S2,
        int layer1) {
    __shared__ ushort As[2][16][136];  // 8.7 KB; +8 pad

    const int lane = threadIdx.x & 63;
    const int wave = threadIdx.x >> 6;
    const int quad = lane >> 4;
    const int l16 = lane & 15;
    const int cb = wave * 32;
    const int lane2 = lane * 2;

    bf16x8 bR[2][4], bT[2][4];
#pragma unroll
    for (int t = 0; t < 2; ++t)
#pragma unroll
        for (int s = 0; s < 4; ++s) {
            int col = cb + t * 16 + l16;
            int k0 = s * 32 + quad * 8;
            bR[t][s] = *reinterpret_cast<const bf16x8*>(Wr + col * F + k0);
            bT[t][s] = *reinterpret_cast<const bf16x8*>(Wt + col * F + k0);
        }
    const float bias0 = bias[cb + l16];
    const float bias1 = bias[cb + 16 + l16];

    float s0 = 0.f, q0 = 0.f, s1 = 0.f, q1 = 0.f;
    int dbuf = 0;

    for (int tile = blockIdx.x; tile < N_TILES; tile += GG_GRID) {
        const int row0 = tile * 16;
        const int nodeb = row0 + wave * 4;
        int2 r0_ = rng[nodeb + 0];
        int2 r1_ = rng[nodeb + 1];
        int2 r2_ = rng[nodeb + 2];
        int2 r3_ = rng[nodeb + 3];
        float ax0 = 0.f, ay0 = 0.f, ax1 = 0.f, ay1 = 0.f;
        float ax2 = 0.f, ay2 = 0.f, ax3 = 0.f, ay3 = 0.f;

        // main: first 16 records of each node guaranteed (ranges padded, min 16)
#pragma unroll 1
        for (int k = 0; k < 16; k += 4) {
            uint4 qa = *reinterpret_cast<const uint4*>(recs + r0_.x + k);
            uint4 qb = *reinterpret_cast<const uint4*>(recs + r1_.x + k);
            uint4 qc = *reinterpret_cast<const uint4*>(recs + r2_.x + k);
            uint4 qd = *reinterpret_cast<const uint4*>(recs + r3_.x + k);
            uint u0 = *reinterpret_cast<const uint*>(featb + (size_t)(qa.x & 0xffffu) * F + lane2);
            uint u1 = *reinterpret_cast<const uint*>(featb + (size_t)(qa.y & 0xffffu) * F + lane2);
            uint u2 = *reinterpret_cast<const uint*>(featb + (size_t)(qa.z & 0xffffu) * F + lane2);
            uint u3 = *reinterpret_cast<const uint*>(featb + (size_t)(qa.w & 0xffffu) * F + lane2);
            uint u4 = *reinterpret_cast<const uint*>(featb + (size_t)(qb.x & 0xffffu) * F + lane2);
            uint u5 = *reinterpret_cast<const uint*>(featb + (size_t)(qb.y & 0xffffu) * F + lane2);
            uint u6 = *reinterpret_cast<const uint*>(featb + (size_t)(qb.z & 0xffffu) * F + lane2);
            uint u7 = *reinterpret_cast<const uint*>(featb + (size_t)(qb.w & 0xffffu) * F + lane2);
            uint u8 = *reinterpret_cast<const uint*>(featb + (size_t)(qc.x & 0xffffu) * F + lane2);
            uint u9 = *reinterpret_cast<const uint*>(featb + (size_t)(qc.y & 0xffffu) * F + lane2);
            uint uA = *reinterpret_cast<const uint*>(featb + (size_t)(qc.z & 0xffffu) * F + lane2);
            uint uB = *reinterpret_cast<const uint*>(featb + (size_t)(qc.w & 0xffffu) * F + lane2);
            uint uC = *reinterpret_cast<const uint*>(featb + (size_t)(qd.x & 0xffffu) * F + lane2);
            uint uD = *reinterpret_cast<const uint*>(featb + (size_t)(qd.y & 0xffffu) * F + lane2);
            uint uE = *reinterpret_cast<const uint*>(featb + (size_t)(qd.z & 0xffffu) * F + lane2);
            uint uF = *reinterpret_cast<const uint*>(featb + (size_t)(qd.w & 0xffffu) * F + lane2);
            float w0 = bf2f((ushort)(qa.x >> 16)), w1 = bf2f((ushort)(qa.y >> 16));
            float w2 = bf2f((ushort)(qa.z >> 16)), w3 = bf2f((ushort)(qa.w >> 16));
            float w4 = bf2f((ushort)(qb.x >> 16)), w5 = bf2f((ushort)(qb.y >> 16));
            float w6 = bf2f((ushort)(qb.z >> 16)), w7 = bf2f((ushort)(qb.w >> 16));
            float w8 = bf2f((ushort)(qc.x >> 16)), w9 = bf2f((ushort)(qc.y >> 16));
            float wA = bf2f((ushort)(qc.z >> 16)), wB = bf2f((ushort)(qc.w >> 16));
            float wC = bf2f((ushort)(qd.x >> 16)), wD = bf2f((ushort)(qd.y >> 16));
            float wE = bf2f((ushort)(qd.z >> 16)), wF = bf2f((ushort)(qd.w >> 16));
            ax0 += w0 * bf2f((ushort)u0) + w1 * bf2f((ushort)u1)
                 + w2 * bf2f((ushort)u2) + w3 * bf2f((ushort)u3);
            ay0 += w0 * bf2f((ushort)(u0 >> 16)) + w1 * bf2f((ushort)(u1 >> 16))
                 + w2 * bf2f((ushort)(u2 >> 16)) + w3 * bf2f((ushort)(u3 >> 16));
            ax1 += w4 * bf2f((ushort)u4) + w5 * bf2f((ushort)u5)
                 + w6 * bf2f((ushort)u6) + w7 * bf2f((ushort)u7);
            ay1 += w4 * bf2f((ushort)(u4 >> 16)) + w5 * bf2f((ushort)(u5 >> 16))
                 + w6 * bf2f((ushort)(u6 >> 16)) + w7 * bf2f((ushort)(u7 >> 16));
            ax2 += w8 * bf2f((ushort)u8) + w9 * bf2f((ushort)u9)
                 + wA * bf2f((ushort)uA) + wB * bf2f((ushort)uB);
            ay2 += w8 * bf2f((ushort)(u8 >> 16)) + w9 * bf2f((ushort)(u9 >> 16))
                 + wA * bf2f((ushort)(uA >> 16)) + wB * bf2f((ushort)(uB >> 16));
            ax3 += wC * bf2f((ushort)uC) + wD * bf2f((ushort)uD)
                 + wE * bf2f((ushort)uE) + wF * bf2f((ushort)uF);
            ay3 += wC * bf2f((ushort)(uC >> 16)) + wD * bf2f((ushort)(uD >> 16))
                 + wE * bf2f((ushort)(uE >> 16)) + wF * bf2f((ushort)(uF >> 16));
        }
        // tail: nodes with >16 records (wave-uniform predication)
        int mx = max(max(r0_.y - r0_.x, r1_.y - r1_.x),
                     max(r2_.y - r2_.x, r3_.y - r3_.x));
#pragma unroll 1
        for (int k = 16; k < mx; k += 4) {
            if (r0_.x + k < r0_.y) {
                uint4 q = *reinterpret_cast<const uint4*>(recs + r0_.x + k);
                uint u0 = *reinterpret_cast<const uint*>(featb + (size_t)(q.x & 0xffffu) * F + lane2);
                uint u1 = *reinterpret_cast<const uint*>(featb + (size_t)(q.y & 0xffffu) * F + lane2);
                uint u2 = *reinterpret_cast<const uint*>(featb + (size_t)(q.z & 0xffffu) * F + lane2);
                uint u3 = *reinterpret_cast<const uint*>(featb + (size_t)(q.w & 0xffffu) * F + lane2);
                float w0 = bf2f((ushort)(q.x >> 16)), w1 = bf2f((ushort)(q.y >> 16));
                float w2 = bf2f((ushort)(q.z >> 16)), w3 = bf2f((ushort)(q.w >> 16));
                ax0 += w0 * bf2f((ushort)u0) + w1 * bf2f((ushort)u1)
                     + w2 * bf2f((ushort)u2) + w3 * bf2f((ushort)u3);
                ay0 += w0 * bf2f((ushort)(u0 >> 16)) + w1 * bf2f((ushort)(u1 >> 16))
                     + w2 * bf2f((ushort)(u2 >> 16)) + w3 * bf2f((ushort)(u3 >> 16));
            }
            if (r1_.x + k < r1_.y) {
                uint4 q = *reinterpret_cast<const uint4*>(recs + r1_.x + k);
                uint u0 = *reinterpret_cast<const uint*>(featb + (size_t)(q.x & 0xffffu) * F + lane2);
                uint u1 = *reinterpret_cast<const uint*>(featb + (size_t)(q.y & 0xffffu) * F + lane2);
                uint u2 = *reinterpret_cast<const uint*>(featb + (size_t)(q.z & 0xffffu) * F + lane2);
                uint u3 = *reinterpret_cast<const uint*>(featb + (size_t)(q.w & 0xffffu) * F + lane2);
                float w0 = bf2f((ushort)(q.x >> 16)), w1 = bf2f((ushort)(q.y >> 16));
                float w2 = bf2f((ushort)(q.z >> 16)), w3 = bf2f((ushort)(q.w >> 16));
                ax1 += w0 * bf2f((ushort)u0) + w1 * bf2f((ushort)u1)
                     + w2 * bf2f((ushort)u2) + w3 * bf2f((ushort)u3);
                ay1 += w0 * bf2f((ushort)(u0 >> 16)) + w1 * bf2f((ushort)(u1 >> 16))
                     + w2 * bf2f((ushort)(u2 >> 16)) + w3 * bf2f((ushort)(u3 >> 16));
            }
            if (r2_.x + k < r2_.y) {
                uint4 q = *reinterpret_cast<const uint4*>(recs + r2_.x + k);
                uint u0 = *reinterpret_cast<const uint*>(featb + (size_t)(q.x & 0xffffu) * F + lane2);
                uint u1 = *reinterpret_cast<const uint*>(featb + (size_t)(q.y & 0xffffu) * F + lane2);
                uint u2 = *reinterpret_cast<const uint*>(featb + (size_t)(q.z & 0xffffu) * F + lane2);
                uint u3 = *reinterpret_cast<const uint*>(featb + (size_t)(q.w & 0xffffu) * F + lane2);
                float w0 = bf2f((ushort)(q.x >> 16)), w1 = bf2f((ushort)(q.y >> 16));
                float w2 = bf2f((ushort)(q.z >> 16)), w3 = bf2f((ushort)(q.w >> 16));
                ax2 += w0 * bf2f((ushort)u0) + w1 * bf2f((ushort)u1)
                     + w2 * bf2f((ushort)u2) + w3 * bf2f((ushort)u3);
                ay2 += w0 * bf2f((ushort)(u0 >> 16)) + w1 * bf2f((ushort)(u1 >> 16))
                     + w2 * bf2f((ushort)(u2 >> 16)) + w3 * bf2f((ushort)(u3 >> 16));
            }
            if (r3_.x + k < r3_.y) {
                uint4 q = *reinterpret_cast<const uint4*>(recs + r3_.x + k);
                uint u0 = *reinterpret_cast<const uint*>(featb + (size_t)(q.x & 0xffffu) * F + lane2);
                uint u1 = *reinterpret_cast<const uint*>(featb + (size_t)(q.y & 0xffffu) * F + lane2);
                uint u2 = *reinterpret_cast<const uint*>(featb + (size_t)(q.z & 0xffffu) * F + lane2);
                uint u3 = *reinterpret_cast<const uint*>(featb + (size_t)(q.w & 0xffffu) * F + lane2);
                float w0 = bf2f((ushort)(q.x >> 16)), w1 = bf2f((ushort)(q.y >> 16));
                float w2 = bf2f((ushort)(q.z >> 16)), w3 = bf2f((ushort)(q.w >> 16));
                ax3 += w0 * bf2f((ushort)u0) + w1 * bf2f((ushort)u1)
                     + w2 * bf2f((ushort)u2) + w3 * bf2f((ushort)u3);
                ay3 += w0 * bf2f((ushort)(u0 >> 16)) + w1 * bf2f((ushort)(u1 >> 16))
                     + w2 * bf2f((ushort)(u2 >> 16)) + w3 * bf2f((ushort)(u3 >> 16));
            }
        }

        *reinterpret_cast<uint*>(&As[dbuf][wave * 4 + 0][lane2]) =
            (uint)f2bf(ax0) | ((uint)f2bf(ay0) << 16);
        *reinterpret_cast<uint*>(&As[dbuf][wave * 4 + 1][lane2]) =
            (uint)f2bf(ax1) | ((uint)f2bf(ay1) << 16);
        *reinterpret_cast<uint*>(&As[dbuf][wave * 4 + 2][lane2]) =
            (uint)f2bf(ax2) | ((uint)f2bf(ay2) << 16);
        *reinterpret_cast<uint*>(&As[dbuf][wave * 4 + 3][lane2]) =
            (uint)f2bf(ax3) | ((uint)f2bf(ay3) << 16);
        __syncthreads();
        // ---- MFMA phase ----
        bf16x8 aR0 = *reinterpret_cast<const bf16x8*>(&As[dbuf][l16][quad * 8]);
        bf16x8 aR1 = *reinterpret_cast<const bf16x8*>(&As[dbuf][l16][quad * 8 + 32]);
        bf16x8 aR2 = *reinterpret_cast<const bf16x8*>(&As[dbuf][l16][quad * 8 + 64]);
        bf16x8 aR3 = *reinterpret_cast<const bf16x8*>(&As[dbuf][l16][quad * 8 + 96]);
        const ushort* tA = featb + (size_t)(row0 + l16) * F + quad * 8;
        bf16x8 aT0 = *reinterpret_cast<const bf16x8*>(tA);
        bf16x8 aT1 = *reinterpret_cast<const bf16x8*>(tA + 32);
        bf16x8 aT2 = *reinterpret_cast<const bf16x8*>(tA + 64);
        bf16x8 aT3 = *reinterpret_cast<const bf16x8*>(tA + 96);

        f32x4 acc0 = {0.f, 0.f, 0.f, 0.f};
        f32x4 acc1 = {0.f, 0.f, 0.f, 0.f};
        acc0 = __builtin_amdgcn_mfma_f32_16x16x32_bf16(aR0, bR[0][0], acc0, 0, 0, 0);
        acc1 = __builtin_amdgcn_mfma_f32_16x16x32_bf16(aR0, bR[1][0], acc1, 0, 0, 0);
        acc0 = __builtin_amdgcn_mfma_f32_16x16x32_bf16(aR1, bR[0][1], acc0, 0, 0, 0);
        acc1 = __builtin_amdgcn_mfma_f32_16x16x32_bf16(aR1, bR[1][1], acc1, 0, 0, 0);
        acc0 = __builtin_amdgcn_mfma_f32_16x16x32_bf16(aR2, bR[0][2], acc0, 0, 0, 0);
        acc1 = __builtin_amdgcn_mfma_f32_16x16x32_bf16(aR2, bR[1][2], acc1, 0, 0, 0);
        acc0 = __builtin_amdgcn_mfma_f32_16x16x32_bf16(aR3, bR[0][3], acc0, 0, 0, 0);
        acc1 = __builtin_amdgcn_mfma_f32_16x16x32_bf16(aR3, bR[1][3], acc1, 0, 0, 0);
        acc0 = __builtin_amdgcn_mfma_f32_16x16x32_bf16(aT0, bT[0][0], acc0, 0, 0, 0);
        acc1 = __builtin_amdgcn_mfma_f32_16x16x32_bf16(aT0, bT[1][0], acc1, 0, 0, 0);
        acc0 = __builtin_amdgcn_mfma_f32_16x16x32_bf16(aT1, bT[0][1], acc0, 0, 0, 0);
        acc1 = __builtin_amdgcn_mfma_f32_16x16x32_bf16(aT1, bT[1][1], acc1, 0, 0, 0);
        acc0 = __builtin_amdgcn_mfma_f32_16x16x32_bf16(aT2, bT[0][2], acc0, 0, 0, 0);
        acc1 = __builtin_amdgcn_mfma_f32_16x16x32_bf16(aT2, bT[1][2], acc1, 0, 0, 0);
        acc0 = __builtin_amdgcn_mfma_f32_16x16x32_bf16(aT3, bT[0][3], acc0, 0, 0, 0);
        acc1 = __builtin_amdgcn_mfma_f32_16x16x32_bf16(aT3, bT[1][3], acc1, 0, 0, 0);

        const int r0 = row0 + quad * 4;  // C layout: col=lane&15, row=quad*4+reg
        if (layer1) {
#pragma unroll
            for (int g = 0; g < 4; ++g) {
                float v0 = acc0[g] + bias0;
                float v1 = acc1[g] + bias1;
                outh[(r0 + g) * F + cb + l16] = f2bf(v0);
                outh[(r0 + g) * F + cb + 16 + l16] = f2bf(v1);
                s0 += v0; q0 += v0 * v0;
                s1 += v1; q1 += v1 * v1;
            }
        } else {
#pragma unroll
            for (int g = 0; g < 4; ++g) {
                out[(r0 + g) * F + cb + l16] = acc0[g] + bias0;
                out[(r0 + g) * F + cb + 16 + l16] = acc1[g] + bias1;
            }
        }
        dbuf ^= 1;
    }

    if (layer1) {
        s0 += __shfl_down(s0, 32); s0 += __shfl_down(s0, 16);
        q0 += __shfl_down(q0, 32); q0 += __shfl_down(q0, 16);
        s1 += __shfl_down(s1, 32); s1 += __shfl_down(s1, 16);
        q1 += __shfl_down(q1, 32); q1 += __shfl_down(q1, 16);
        if (lane < 16) {
            unsafeAtomicAdd(&S[cb + lane], s0);
            unsafeAtomicAdd(&S2[cb + lane], q0);
            unsafeAtomicAdd(&S[cb + 16 + lane], s1);
            unsafeAtomicAdd(&S2[cb + 16 + lane], q1);
        }
    }
}

// ============ BN finalize (inline) + RReLU: hraw (bf16) -> hb (bf16) ============
__global__ __launch_bounds__(256) void norm_act_k(const ushort* __restrict__ hraw,
        const float* __restrict__ S, const float* __restrict__ S2,
        const float* __restrict__ gamma, const float* __restrict__ beta,
        ushort* __restrict__ hb) {
    __shared__ float sc_s[128], sh_s[128];
    if (threadIdx.x < 128) {
        int j = threadIdx.x;
        float mean = S[j] * (1.f / N_NODES);
        float var = S2[j] * (1.f / N_NODES) - mean * mean;
        float inv = rsqrtf(var + BN_EPS);
        float sc = gamma[j] * inv;
        sc_s[j] = sc;
        sh_s[j] = beta[j] - mean * sc;
    }
    __syncthreads();
    int i = blockIdx.x * 256 + threadIdx.x;  // 4 bf16 per thread
    int cbase = (i & 31) * 4;
    uint2 u = reinterpret_cast<const uint2*>(hraw)[i];
    float4 v = make_float4(bf2f((ushort)u.x), bf2f((ushort)(u.x >> 16)),
                           bf2f((ushort)u.y), bf2f((ushort)(u.y >> 16)));
    float4 sc = *reinterpret_cast<const float4*>(&sc_s[cbase]);
    float4 sh = *reinterpret_cast<const float4*>(&sh_s[cbase]);
    v.x = v.x * sc.x + sh.x;
    v.y = v.y * sc.y + sh.y;
    v.z = v.z * sc.z + sh.z;
    v.w = v.w * sc.w + sh.w;
    v.x = v.x >= 0.f ? v.x : v.x * SLOPE;
    v.y = v.y >= 0.f ? v.y : v.y * SLOPE;
    v.z = v.z >= 0.f ? v.z : v.z * SLOPE;
    v.w = v.w >= 0.f ? v.w : v.w * SLOPE;
    uint2 o;
    o.x = (uint)f2bf(v.x) | ((uint)f2bf(v.y) << 16);
    o.y = (uint)f2bf(v.z) | ((uint)f2bf(v.w) << 16);
    reinterpret_cast<uint2*>(hb)[i] = o;
}

extern "C" void kernel_launch(void* const* d_in, const int* in_sizes, int n_in,
                              void* d_out, int out_size, void* d_ws, size_t ws_size,
                              hipStream_t stream) {
    const float* x     = (const float*)d_in[0];
    const int*   ei    = (const int*)d_in[1];
    const float* ea    = (const float*)d_in[2];
    const float* W1r   = (const float*)d_in[3];
    const float* b1    = (const float*)d_in[4];
    const float* W1t   = (const float*)d_in[5];
    const float* gamma = (const float*)d_in[6];
    const float* beta  = (const float*)d_in[7];
    const float* W2r   = (const float*)d_in[8];
    const float* b2    = (const float*)d_in[9];
    const float* W2t   = (const float*)d_in[10];
    float* out = (float*)d_out;

    char* ws = (char*)d_ws;
    size_t off = 0;
    u64*    stg   = (u64*)(ws + off);    off += (size_t)NBKT * BKT_CAP * 8;  // 12.85 MB
    ushort* featb = (ushort*)(ws + off); off += (size_t)N_NODES * F * 2;     // 12.8 MB (xb -> hb)
    uint*   recs  = (uint*)(ws + off);   off += (size_t)REC_CAP * 4;         // 6.4 MB (no memset needed)
    int*    bcur  = (int*)(ws + off);    off += 256 * 4;                     // memset 0
    float*  S     = (float*)(ws + off);  off += 128 * 4;                     // memset 0
    float*  S2    = (float*)(ws + off);  off += 128 * 4;                     // memset 0
    int2*   rng   = (int2*)(ws + off);   off += (size_t)N_NODES * 8;         // 400 KB
    ushort* wb    = (ushort*)(ws + off); off += 4 * 16384 * 2;               // 128 KB
    ushort* hraw  = (ushort*)d_out;      // bf16 h in d_out storage (gg2 overwrites)

    const int* srcp = ei;
    const int* tgtp = ei + N_EDGES;

    // tiny memset: bcur (cursors) + S/S2 (stats accum) — recs no longer needs zeroing
    hipMemsetAsync(bcur, 0, 256 * 4 + 256 * 4, stream);
    s1p_k<<<P1_BLKS + CASTX_BLKS + CASTW_BLKS, 256, 0, stream>>>(
        srcp, tgtp, ea, bcur, stg, x, featb, W1r, W1t, W2r, W2t, wb);
    sort2_k<<<NBKT, 256, 0, stream>>>(bcur, stg, recs, rng);

    // ---- layer 1: fused gather+GEMM (+BN stats), bf16 h into d_out storage ----
    gg_k<<<GG_GRID, 256, 0, stream>>>(featb, rng, recs, wb, wb + 16384, b1,
                                      out, hraw, S, S2, 1);
    norm_act_k<<<CASTX_BLKS, 256, 0, stream>>>(hraw, S, S2, gamma, beta, featb);
    // ---- layer 2: fused gather+GEMM, fp32 out ----
    gg_k<<<GG_GRID, 256, 0, stream>>>(featb, rng, recs, wb + 32768, wb + 49152, b2,
                                      out, hraw, S, S2, 0);
}

// Round 10
// 265.101 us; speedup vs baseline: 1.2643x; 1.2643x over previous
//
#include <hip/hip_runtime.h>

#define N_NODES 50000
#define N_EDGES 800000
#define F 128
#define BN_EPS 1e-5f
#define SLOPE 0.22916666666666666f  // RReLU eval slope 11/48

#define NBKT 196          // coarse buckets (tgt>>8)
#define BKT_CAP 8192      // staging slots per bucket (mean 4096)
#define P1_CHUNK 4096
#define P1_EPB 16
#define P1_BLKS 196       // ceil(N_EDGES/P1_CHUNK)
#define CASTX_BLKS 6250   // N_NODES*F/4/256 (exact)
#define CASTW_BLKS 64
#define BKT_FINAL_CAP 9984   // cnt_max + 256*7 pad slack; 39.9 KB LDS
#define REC_CAP 1160192      // 800000 + 196*1792 + slack (pad-to-8)
#define N_TILES 3125      // N_NODES/16 (exact)
#define GG_GRID 2048      // 8 blocks/CU -> 100% wave cap (R6 had 1024 -> 50% cap)

typedef __attribute__((ext_vector_type(8))) short bf16x8;
typedef __attribute__((ext_vector_type(4))) float f32x4;
typedef unsigned long long u64;

__device__ __forceinline__ float bf2f(ushort u) {
    union { uint i; float f; } v; v.i = (uint)u << 16; return v.f;
}
__device__ __forceinline__ ushort f2bf(float f) {
    union { float f; uint i; } v; v.f = f;
    uint r = v.i + 0x7fffu + ((v.i >> 16) & 1u);  // RNE
    return (ushort)(r >> 16);
}

// ============ s1p: sort pass 1 (bucket binning) + x/W bf16 casts, one launch ============
// staging record: bits[0:31] = src | bf16(w)<<16 ; bits[32:63] = tgt
__global__ __launch_bounds__(256) void s1p_k(const int* __restrict__ src,
        const int* __restrict__ tgt, const float* __restrict__ ew,
        int* __restrict__ bcur, u64* __restrict__ stg,
        const float* __restrict__ x, ushort* __restrict__ xb,
        const float* __restrict__ W1r, const float* __restrict__ W1t,
        const float* __restrict__ W2r, const float* __restrict__ W2t,
        ushort* __restrict__ wb) {
    const int b = blockIdx.x;
    if (b >= P1_BLKS) {
        if (b < P1_BLKS + CASTX_BLKS) {
            int i = (b - P1_BLKS) * 256 + threadIdx.x;
            float4 v = reinterpret_cast<const float4*>(x)[i];
            ushort4 o;
            o.x = f2bf(v.x); o.y = f2bf(v.y); o.z = f2bf(v.z); o.w = f2bf(v.w);
            reinterpret_cast<ushort4*>(xb)[i] = o;
        } else {
            int i = (b - P1_BLKS - CASTX_BLKS) * 256 + threadIdx.x;  // 16384 total
            int m = i >> 12;
            int j = i & 4095;
            const float* sp = (m == 0) ? W1r : (m == 1) ? W1t : (m == 2) ? W2r : W2t;
            float4 v = reinterpret_cast<const float4*>(sp)[j];
            ushort4 o;
            o.x = f2bf(v.x); o.y = f2bf(v.y); o.z = f2bf(v.z); o.w = f2bf(v.w);
            reinterpret_cast<ushort4*>(wb)[i] = o;
        }
        return;
    }
    // ---- sort pass 1 ----
    __shared__ uint cnt[256];
    __shared__ uint base[256];
    __shared__ uint lcur[256];
    __shared__ uint gbase[256];
    __shared__ u64 lrec[P1_CHUNK];  // 32 KB

    const int e0 = b * P1_CHUNK;
    const int nE = min(P1_CHUNK, N_EDGES - e0);
    cnt[threadIdx.x] = 0;
    __syncthreads();

    u64 myrec[P1_EPB];
    bool myok[P1_EPB];
#pragma unroll
    for (int k = 0; k < P1_EPB; ++k) {
        int idx = threadIdx.x + (k << 8);
        bool ok = idx < nE;
        myok[k] = ok;
        if (ok) {
            int e = e0 + idx;
            uint t = (uint)tgt[e];
            uint lo = (uint)(ushort)src[e] | ((uint)f2bf(ew[e]) << 16);
            myrec[k] = (u64)lo | ((u64)t << 32);
            atomicAdd(&cnt[t >> 8], 1u);
        }
    }
    __syncthreads();
    uint v = cnt[threadIdx.x];
    base[threadIdx.x] = v;
    __syncthreads();
    for (int o = 1; o < 256; o <<= 1) {
        uint t = (threadIdx.x >= (unsigned)o) ? base[threadIdx.x - o] : 0;
        __syncthreads();
        base[threadIdx.x] += t;
        __syncthreads();
    }
    uint excl = base[threadIdx.x] - v;
    base[threadIdx.x] = excl;
    lcur[threadIdx.x] = excl;
    if (threadIdx.x < NBKT && v > 0)
        gbase[threadIdx.x] = (uint)threadIdx.x * BKT_CAP +
                             (uint)atomicAdd(&bcur[threadIdx.x], (int)v);
    __syncthreads();
#pragma unroll
    for (int k = 0; k < P1_EPB; ++k) {
        if (myok[k]) {
            uint bb = (uint)(myrec[k] >> 40);
            uint slot = atomicAdd(&lcur[bb], 1u);
            lrec[slot] = myrec[k];
        }
    }
    __syncthreads();
    for (int s = threadIdx.x; s < nE; s += 256) {
        u64 r = lrec[s];
        uint bb = (uint)(r >> 40);
        stg[gbase[bb] + ((uint)s - base[bb])] = r;
    }
}

// ============ sort pass 2: per bucket -> final recs (pad-8, zero filler) via LDS ====
__global__ __launch_bounds__(256) void sort2_k(const int* __restrict__ bcur,
        const u64* __restrict__ stg, uint* __restrict__ recs, int2* __restrict__ rng) {
    __shared__ int lcnt[256];
    __shared__ int lcur[256];
    __shared__ int sc[256];
    __shared__ int fbase_s;
    __shared__ uint lrec[BKT_FINAL_CAP];  // 39.9 KB
    const int b = blockIdx.x;
    const int tid = threadIdx.x;

    // redundant per-block scan of bucket strides -> this bucket's final base
    int cnt_t = (tid < NBKT) ? bcur[tid] : 0;
    int stride_t = (tid < NBKT) ? (((cnt_t + 7) & ~7) + 1792) : 0;
    sc[tid] = stride_t;
    lcnt[tid] = 0;
    __syncthreads();
    for (int o = 1; o < 256; o <<= 1) {
        int t = (tid >= o) ? sc[tid - o] : 0;
        __syncthreads();
        sc[tid] += t;
        __syncthreads();
    }
    if (tid == b) fbase_s = sc[tid] - stride_t;  // exclusive
    __syncthreads();
    const int fbase = fbase_s;
    const int cnt = bcur[b];
    const u64* sb = stg + (size_t)b * BKT_CAP;

    // per-node counts
    for (int i = tid; i < cnt; i += 256)
        atomicAdd(&lcnt[(int)(sb[i] >> 32) & 255], 1);
    __syncthreads();
    const int node = b * 256 + tid;
    int myc = lcnt[tid];
    int myp = (myc + 7) & ~7;            // pad to x8 (zero filler = exact no-op)
    if (node >= N_NODES) myp = 0;
    sc[tid] = myp;
    __syncthreads();
    for (int o = 1; o < 256; o <<= 1) {
        int t = (tid >= o) ? sc[tid - o] : 0;
        __syncthreads();
        sc[tid] += t;
        __syncthreads();
    }
    const int myoff = sc[tid] - myp;     // exclusive local offset
    const int ptot = sc[255];            // total padded slots this bucket
    lcur[tid] = myoff;
    if (node < N_NODES) rng[node] = make_int2(fbase + myoff, fbase + myoff + myp);
    // zero-fill (filler records: src=0, w=+0)
    for (int i = tid; i < ptot; i += 256) lrec[i] = 0;
    __syncthreads();
    // place records
    for (int i = tid; i < cnt; i += 256) {
        u64 r = sb[i];
        int n = (int)(r >> 32) & 255;
        int p = atomicAdd(&lcur[n], 1);
        lrec[p] = (uint)r;
    }
    __syncthreads();
    // coalesced dump
    for (int i = tid; i < ptot; i += 256) recs[fbase + i] = lrec[i];
}

// ============ fused gather + dual MFMA GEMM (+BN stats for layer 1) ============
// grid-stride over 16-row tiles; wave w gathers rows w*4..w*4+3 into LDS, then MFMA.
// (R6 shape: sequential per-node 8-wide gather -> VGPR ~64; GG_GRID=2048 -> 8 blk/CU)
__global__ __launch_bounds__(256) void gg_k(const ushort* __restrict__ featb,
        const int2* __restrict__ rng, const uint* __restrict__ recs,
        const ushort* __restrict__ Wr, const ushort* __restrict__ Wt,
        const float* __restrict__ bias, float* __restrict__ out,
        ushort* __restrict__ outh, float* __restrict__ S, float* __restrict__ S2,
        int layer1) {
    __shared__ ushort As[2][16][136];  // 8.7 KB; +8 pad

    const int lane = threadIdx.x & 63;
    const int wave = threadIdx.x >> 6;
    const int quad = lane >> 4;
    const int l16 = lane & 15;
    const int cb = wave * 32;
    const int lane2 = lane * 2;

    bf16x8 bR[2][4], bT[2][4];
#pragma unroll
    for (int t = 0; t < 2; ++t)
#pragma unroll
        for (int s = 0; s < 4; ++s) {
            int col = cb + t * 16 + l16;
            int k0 = s * 32 + quad * 8;
            bR[t][s] = *reinterpret_cast<const bf16x8*>(Wr + col * F + k0);
            bT[t][s] = *reinterpret_cast<const bf16x8*>(Wt + col * F + k0);
        }
    const float bias0 = bias[cb + l16];
    const float bias1 = bias[cb + 16 + l16];

    float s0 = 0.f, q0 = 0.f, s1 = 0.f, q1 = 0.f;
    int dbuf = 0;

    for (int tile = blockIdx.x; tile < N_TILES; tile += GG_GRID) {
        const int row0 = tile * 16;
        // ---- gather phase: wave w gathers rows w*4 .. w*4+3 of this tile ----
#pragma unroll
        for (int g = 0; g < 4; ++g) {
            int node = row0 + wave * 4 + g;
            int2 r = rng[node];
            float a0 = 0.f, a1 = 0.f;
            for (int p = r.x; p < r.y; p += 8) {
                uint4 ra = *reinterpret_cast<const uint4*>(recs + p);
                uint4 rb = *reinterpret_cast<const uint4*>(recs + p + 4);
                uint u0 = *reinterpret_cast<const uint*>(featb + (size_t)(ra.x & 0xffffu) * F + lane2);
                uint u1 = *reinterpret_cast<const uint*>(featb + (size_t)(ra.y & 0xffffu) * F + lane2);
                uint u2 = *reinterpret_cast<const uint*>(featb + (size_t)(ra.z & 0xffffu) * F + lane2);
                uint u3 = *reinterpret_cast<const uint*>(featb + (size_t)(ra.w & 0xffffu) * F + lane2);
                uint u4 = *reinterpret_cast<const uint*>(featb + (size_t)(rb.x & 0xffffu) * F + lane2);
                uint u5 = *reinterpret_cast<const uint*>(featb + (size_t)(rb.y & 0xffffu) * F + lane2);
                uint u6 = *reinterpret_cast<const uint*>(featb + (size_t)(rb.z & 0xffffu) * F + lane2);
                uint u7 = *reinterpret_cast<const uint*>(featb + (size_t)(rb.w & 0xffffu) * F + lane2);
                float w0 = bf2f((ushort)(ra.x >> 16)), w1 = bf2f((ushort)(ra.y >> 16));
                float w2 = bf2f((ushort)(ra.z >> 16)), w3 = bf2f((ushort)(ra.w >> 16));
                float w4 = bf2f((ushort)(rb.x >> 16)), w5 = bf2f((ushort)(rb.y >> 16));
                float w6 = bf2f((ushort)(rb.z >> 16)), w7 = bf2f((ushort)(rb.w >> 16));
                a0 += w0 * bf2f((ushort)u0) + w1 * bf2f((ushort)u1)
                    + w2 * bf2f((ushort)u2) + w3 * bf2f((ushort)u3)
                    + w4 * bf2f((ushort)u4) + w5 * bf2f((ushort)u5)
                    + w6 * bf2f((ushort)u6) + w7 * bf2f((ushort)u7);
                a1 += w0 * bf2f((ushort)(u0 >> 16)) + w1 * bf2f((ushort)(u1 >> 16))
                    + w2 * bf2f((ushort)(u2 >> 16)) + w3 * bf2f((ushort)(u3 >> 16))
                    + w4 * bf2f((ushort)(u4 >> 16)) + w5 * bf2f((ushort)(u5 >> 16))
                    + w6 * bf2f((ushort)(u6 >> 16)) + w7 * bf2f((ushort)(u7 >> 16));
            }
            *reinterpret_cast<uint*>(&As[dbuf][wave * 4 + g][lane2]) =
                (uint)f2bf(a0) | ((uint)f2bf(a1) << 16);
        }
        __syncthreads();
        // ---- MFMA phase ----
        bf16x8 aR0 = *reinterpret_cast<const bf16x8*>(&As[dbuf][l16][quad * 8]);
        bf16x8 aR1 = *reinterpret_cast<const bf16x8*>(&As[dbuf][l16][quad * 8 + 32]);
        bf16x8 aR2 = *reinterpret_cast<const bf16x8*>(&As[dbuf][l16][quad * 8 + 64]);
        bf16x8 aR3 = *reinterpret_cast<const bf16x8*>(&As[dbuf][l16][quad * 8 + 96]);
        const ushort* tA = featb + (size_t)(row0 + l16) * F + quad * 8;
        bf16x8 aT0 = *reinterpret_cast<const bf16x8*>(tA);
        bf16x8 aT1 = *reinterpret_cast<const bf16x8*>(tA + 32);
        bf16x8 aT2 = *reinterpret_cast<const bf16x8*>(tA + 64);
        bf16x8 aT3 = *reinterpret_cast<const bf16x8*>(tA + 96);

        f32x4 acc0 = {0.f, 0.f, 0.f, 0.f};
        f32x4 acc1 = {0.f, 0.f, 0.f, 0.f};
        acc0 = __builtin_amdgcn_mfma_f32_16x16x32_bf16(aR0, bR[0][0], acc0, 0, 0, 0);
        acc1 = __builtin_amdgcn_mfma_f32_16x16x32_bf16(aR0, bR[1][0], acc1, 0, 0, 0);
        acc0 = __builtin_amdgcn_mfma_f32_16x16x32_bf16(aR1, bR[0][1], acc0, 0, 0, 0);
        acc1 = __builtin_amdgcn_mfma_f32_16x16x32_bf16(aR1, bR[1][1], acc1, 0, 0, 0);
        acc0 = __builtin_amdgcn_mfma_f32_16x16x32_bf16(aR2, bR[0][2], acc0, 0, 0, 0);
        acc1 = __builtin_amdgcn_mfma_f32_16x16x32_bf16(aR2, bR[1][2], acc1, 0, 0, 0);
        acc0 = __builtin_amdgcn_mfma_f32_16x16x32_bf16(aR3, bR[0][3], acc0, 0, 0, 0);
        acc1 = __builtin_amdgcn_mfma_f32_16x16x32_bf16(aR3, bR[1][3], acc1, 0, 0, 0);
        acc0 = __builtin_amdgcn_mfma_f32_16x16x32_bf16(aT0, bT[0][0], acc0, 0, 0, 0);
        acc1 = __builtin_amdgcn_mfma_f32_16x16x32_bf16(aT0, bT[1][0], acc1, 0, 0, 0);
        acc0 = __builtin_amdgcn_mfma_f32_16x16x32_bf16(aT1, bT[0][1], acc0, 0, 0, 0);
        acc1 = __builtin_amdgcn_mfma_f32_16x16x32_bf16(aT1, bT[1][1], acc1, 0, 0, 0);
        acc0 = __builtin_amdgcn_mfma_f32_16x16x32_bf16(aT2, bT[0][2], acc0, 0, 0, 0);
        acc1 = __builtin_amdgcn_mfma_f32_16x16x32_bf16(aT2, bT[1][2], acc1, 0, 0, 0);
        acc0 = __builtin_amdgcn_mfma_f32_16x16x32_bf16(aT3, bT[0][3], acc0, 0, 0, 0);
        acc1 = __builtin_amdgcn_mfma_f32_16x16x32_bf16(aT3, bT[1][3], acc1, 0, 0, 0);

        const int r0 = row0 + quad * 4;  // C layout: col=lane&15, row=quad*4+reg
        if (layer1) {
#pragma unroll
            for (int g = 0; g < 4; ++g) {
                float v0 = acc0[g] + bias0;
                float v1 = acc1[g] + bias1;
                outh[(r0 + g) * F + cb + l16] = f2bf(v0);
                outh[(r0 + g) * F + cb + 16 + l16] = f2bf(v1);
                s0 += v0; q0 += v0 * v0;
                s1 += v1; q1 += v1 * v1;
            }
        } else {
#pragma unroll
            for (int g = 0; g < 4; ++g) {
                out[(r0 + g) * F + cb + l16] = acc0[g] + bias0;
                out[(r0 + g) * F + cb + 16 + l16] = acc1[g] + bias1;
            }
        }
        dbuf ^= 1;
    }

    if (layer1) {
        s0 += __shfl_down(s0, 32); s0 += __shfl_down(s0, 16);
        q0 += __shfl_down(q0, 32); q0 += __shfl_down(q0, 16);
        s1 += __shfl_down(s1, 32); s1 += __shfl_down(s1, 16);
        q1 += __shfl_down(q1, 32); q1 += __shfl_down(q1, 16);
        if (lane < 16) {
            unsafeAtomicAdd(&S[cb + lane], s0);
            unsafeAtomicAdd(&S2[cb + lane], q0);
            unsafeAtomicAdd(&S[cb + 16 + lane], s1);
            unsafeAtomicAdd(&S2[cb + 16 + lane], q1);
        }
    }
}

// ============ BN finalize (inline) + RReLU: hraw (bf16) -> hb (bf16) ============
__global__ __launch_bounds__(256) void norm_act_k(const ushort* __restrict__ hraw,
        const float* __restrict__ S, const float* __restrict__ S2,
        const float* __restrict__ gamma, const float* __restrict__ beta,
        ushort* __restrict__ hb) {
    __shared__ float sc_s[128], sh_s[128];
    if (threadIdx.x < 128) {
        int j = threadIdx.x;
        float mean = S[j] * (1.f / N_NODES);
        float var = S2[j] * (1.f / N_NODES) - mean * mean;
        float inv = rsqrtf(var + BN_EPS);
        float sc = gamma[j] * inv;
        sc_s[j] = sc;
        sh_s[j] = beta[j] - mean * sc;
    }
    __syncthreads();
    int i = blockIdx.x * 256 + threadIdx.x;  // 4 bf16 per thread
    int cbase = (i & 31) * 4;
    uint2 u = reinterpret_cast<const uint2*>(hraw)[i];
    float4 v = make_float4(bf2f((ushort)u.x), bf2f((ushort)(u.x >> 16)),
                           bf2f((ushort)u.y), bf2f((ushort)(u.y >> 16)));
    float4 sc = *reinterpret_cast<const float4*>(&sc_s[cbase]);
    float4 sh = *reinterpret_cast<const float4*>(&sh_s[cbase]);
    v.x = v.x * sc.x + sh.x;
    v.y = v.y * sc.y + sh.y;
    v.z = v.z * sc.z + sh.z;
    v.w = v.w * sc.w + sh.w;
    v.x = v.x >= 0.f ? v.x : v.x * SLOPE;
    v.y = v.y >= 0.f ? v.y : v.y * SLOPE;
    v.z = v.z >= 0.f ? v.z : v.z * SLOPE;
    v.w = v.w >= 0.f ? v.w : v.w * SLOPE;
    uint2 o;
    o.x = (uint)f2bf(v.x) | ((uint)f2bf(v.y) << 16);
    o.y = (uint)f2bf(v.z) | ((uint)f2bf(v.w) << 16);
    reinterpret_cast<uint2*>(hb)[i] = o;
}

extern "C" void kernel_launch(void* const* d_in, const int* in_sizes, int n_in,
                              void* d_out, int out_size, void* d_ws, size_t ws_size,
                              hipStream_t stream) {
    const float* x     = (const float*)d_in[0];
    const int*   ei    = (const int*)d_in[1];
    const float* ea    = (const float*)d_in[2];
    const float* W1r   = (const float*)d_in[3];
    const float* b1    = (const float*)d_in[4];
    const float* W1t   = (const float*)d_in[5];
    const float* gamma = (const float*)d_in[6];
    const float* beta  = (const float*)d_in[7];
    const float* W2r   = (const float*)d_in[8];
    const float* b2    = (const float*)d_in[9];
    const float* W2t   = (const float*)d_in[10];
    float* out = (float*)d_out;

    char* ws = (char*)d_ws;
    size_t off = 0;
    u64*    stg   = (u64*)(ws + off);    off += (size_t)NBKT * BKT_CAP * 8;  // 12.85 MB
    ushort* featb = (ushort*)(ws + off); off += (size_t)N_NODES * F * 2;     // 12.8 MB (xb -> hb)
    uint*   recs  = (uint*)(ws + off);   off += (size_t)REC_CAP * 4;         // 4.6 MB (no memset)
    int*    bcur  = (int*)(ws + off);    off += 256 * 4;                     // memset 0
    float*  S     = (float*)(ws + off);  off += 128 * 4;                     // memset 0
    float*  S2    = (float*)(ws + off);  off += 128 * 4;                     // memset 0
    int2*   rng   = (int2*)(ws + off);   off += (size_t)N_NODES * 8;         // 400 KB
    ushort* wb    = (ushort*)(ws + off); off += 4 * 16384 * 2;               // 128 KB
    ushort* hraw  = (ushort*)d_out;      // bf16 h in d_out storage (gg2 overwrites)

    const int* srcp = ei;
    const int* tgtp = ei + N_EDGES;

    // tiny memset: bcur (cursors) + S/S2 (stats accum)
    hipMemsetAsync(bcur, 0, 256 * 4 + 256 * 4, stream);
    s1p_k<<<P1_BLKS + CASTX_BLKS + CASTW_BLKS, 256, 0, stream>>>(
        srcp, tgtp, ea, bcur, stg, x, featb, W1r, W1t, W2r, W2t, wb);
    sort2_k<<<NBKT, 256, 0, stream>>>(bcur, stg, recs, rng);

    // ---- layer 1: fused gather+GEMM (+BN stats), bf16 h into d_out storage ----
    gg_k<<<GG_GRID, 256, 0, stream>>>(featb, rng, recs, wb, wb + 16384, b1,
                                      out, hraw, S, S2, 1);
    norm_act_k<<<CASTX_BLKS, 256, 0, stream>>>(hraw, S, S2, gamma, beta, featb);
    // ---- layer 2: fused gather+GEMM, fp32 out ----
    gg_k<<<GG_GRID, 256, 0, stream>>>(featb, rng, recs, wb + 32768, wb + 49152, b2,
                                      out, hraw, S, S2, 0);
}

// Round 11
// 231.071 us; speedup vs baseline: 1.4504x; 1.1473x over previous
//
#include <hip/hip_runtime.h>

#define N_NODES 50000
#define N_EDGES 800000
#define F 128
#define BN_EPS 1e-5f
#define SLOPE 0.22916666666666666f  // RReLU eval slope 11/48

#define NBKT 196          // coarse buckets (tgt>>8)
#define BKT_CAP 8192      // staging slots per bucket (mean 4082)
#define P1_CHUNK 4096
#define P1_EPB 16
#define P1_BLKS 196       // ceil(N_EDGES/P1_CHUNK)
#define CASTX_BLKS 6250   // N_NODES*F/4/256 (exact)
#define CASTW_BLKS 64
#define BKT_FINAL_CAP 9984   // cnt_max + 256*7 pad slack; 39.9 KB LDS
#define REC_CAP 1160192      // 800000 + 196*1792 + slack (pad-to-8)
#define N_RT 3125         // N_NODES/16 row-tiles (exact)
#define GEMM_GRID 512

typedef __attribute__((ext_vector_type(8))) short bf16x8;
typedef __attribute__((ext_vector_type(4))) float f32x4;
typedef unsigned long long u64;

__device__ __forceinline__ float bf2f(ushort u) {
    union { uint i; float f; } v; v.i = (uint)u << 16; return v.f;
}
__device__ __forceinline__ ushort f2bf(float f) {
    union { float f; uint i; } v; v.f = f;
    uint r = v.i + 0x7fffu + ((v.i >> 16) & 1u);  // RNE
    return (ushort)(r >> 16);
}

// ============ s1p: sort pass 1 (bucket binning) + x/W bf16 casts, one launch ============
// staging record: bits[0:31] = src | bf16(w)<<16 ; bits[32:63] = tgt
__global__ __launch_bounds__(256) void s1p_k(const int* __restrict__ src,
        const int* __restrict__ tgt, const float* __restrict__ ew,
        int* __restrict__ bcur, u64* __restrict__ stg,
        const float* __restrict__ x, ushort* __restrict__ xb,
        const float* __restrict__ W1r, const float* __restrict__ W1t,
        const float* __restrict__ W2r, const float* __restrict__ W2t,
        ushort* __restrict__ wb) {
    const int b = blockIdx.x;
    if (b >= P1_BLKS) {
        if (b < P1_BLKS + CASTX_BLKS) {
            int i = (b - P1_BLKS) * 256 + threadIdx.x;
            float4 v = reinterpret_cast<const float4*>(x)[i];
            ushort4 o;
            o.x = f2bf(v.x); o.y = f2bf(v.y); o.z = f2bf(v.z); o.w = f2bf(v.w);
            reinterpret_cast<ushort4*>(xb)[i] = o;
        } else {
            int i = (b - P1_BLKS - CASTX_BLKS) * 256 + threadIdx.x;  // 16384 total
            int m = i >> 12;
            int j = i & 4095;
            const float* sp = (m == 0) ? W1r : (m == 1) ? W1t : (m == 2) ? W2r : W2t;
            float4 v = reinterpret_cast<const float4*>(sp)[j];
            ushort4 o;
            o.x = f2bf(v.x); o.y = f2bf(v.y); o.z = f2bf(v.z); o.w = f2bf(v.w);
            reinterpret_cast<ushort4*>(wb)[i] = o;
        }
        return;
    }
    // ---- sort pass 1 ----
    __shared__ uint cnt[256];
    __shared__ uint base[256];
    __shared__ uint lcur[256];
    __shared__ uint gbase[256];
    __shared__ u64 lrec[P1_CHUNK];  // 32 KB

    const int e0 = b * P1_CHUNK;
    const int nE = min(P1_CHUNK, N_EDGES - e0);
    cnt[threadIdx.x] = 0;
    __syncthreads();

    u64 myrec[P1_EPB];
    bool myok[P1_EPB];
#pragma unroll
    for (int k = 0; k < P1_EPB; ++k) {
        int idx = threadIdx.x + (k << 8);
        bool ok = idx < nE;
        myok[k] = ok;
        if (ok) {
            int e = e0 + idx;
            uint t = (uint)tgt[e];
            uint lo = (uint)(ushort)src[e] | ((uint)f2bf(ew[e]) << 16);
            myrec[k] = (u64)lo | ((u64)t << 32);
            atomicAdd(&cnt[t >> 8], 1u);
        }
    }
    __syncthreads();
    uint v = cnt[threadIdx.x];
    base[threadIdx.x] = v;
    __syncthreads();
    for (int o = 1; o < 256; o <<= 1) {
        uint t = (threadIdx.x >= (unsigned)o) ? base[threadIdx.x - o] : 0;
        __syncthreads();
        base[threadIdx.x] += t;
        __syncthreads();
    }
    uint excl = base[threadIdx.x] - v;
    base[threadIdx.x] = excl;
    lcur[threadIdx.x] = excl;
    if (threadIdx.x < NBKT && v > 0)
        gbase[threadIdx.x] = (uint)threadIdx.x * BKT_CAP +
                             (uint)atomicAdd(&bcur[threadIdx.x], (int)v);
    __syncthreads();
#pragma unroll
    for (int k = 0; k < P1_EPB; ++k) {
        if (myok[k]) {
            uint bb = (uint)(myrec[k] >> 40);
            uint slot = atomicAdd(&lcur[bb], 1u);
            lrec[slot] = myrec[k];
        }
    }
    __syncthreads();
    for (int s = threadIdx.x; s < nE; s += 256) {
        u64 r = lrec[s];
        uint bb = (uint)(r >> 40);
        stg[gbase[bb] + ((uint)s - base[bb])] = r;
    }
}

// ============ sort pass 2: per bucket -> final recs (pad-8, zero filler) via LDS ====
__global__ __launch_bounds__(256) void sort2_k(const int* __restrict__ bcur,
        const u64* __restrict__ stg, uint* __restrict__ recs, int2* __restrict__ rng) {
    __shared__ int lcnt[256];
    __shared__ int lcur[256];
    __shared__ int sc[256];
    __shared__ int fbase_s;
    __shared__ uint lrec[BKT_FINAL_CAP];  // 39.9 KB
    const int b = blockIdx.x;
    const int tid = threadIdx.x;

    // redundant per-block scan of bucket strides -> this bucket's final base
    int cnt_t = (tid < NBKT) ? bcur[tid] : 0;
    int stride_t = (tid < NBKT) ? (((cnt_t + 7) & ~7) + 1792) : 0;
    sc[tid] = stride_t;
    lcnt[tid] = 0;
    __syncthreads();
    for (int o = 1; o < 256; o <<= 1) {
        int t = (tid >= o) ? sc[tid - o] : 0;
        __syncthreads();
        sc[tid] += t;
        __syncthreads();
    }
    if (tid == b) fbase_s = sc[tid] - stride_t;  // exclusive
    __syncthreads();
    const int fbase = fbase_s;
    const int cnt = bcur[b];
    const u64* sb = stg + (size_t)b * BKT_CAP;

    // per-node counts
    for (int i = tid; i < cnt; i += 256)
        atomicAdd(&lcnt[(int)(sb[i] >> 32) & 255], 1);
    __syncthreads();
    const int node = b * 256 + tid;
    int myc = lcnt[tid];
    int myp = (myc + 7) & ~7;            // pad to x8 (zero filler = exact no-op)
    if (node >= N_NODES) myp = 0;
    sc[tid] = myp;
    __syncthreads();
    for (int o = 1; o < 256; o <<= 1) {
        int t = (tid >= o) ? sc[tid - o] : 0;
        __syncthreads();
        sc[tid] += t;
        __syncthreads();
    }
    const int myoff = sc[tid] - myp;     // exclusive local offset
    const int ptot = sc[255];            // total padded slots this bucket
    lcur[tid] = myoff;
    if (node < N_NODES) rng[node] = make_int2(fbase + myoff, fbase + myoff + myp);
    // zero-fill (filler records: src=0, w=+0)
    for (int i = tid; i < ptot; i += 256) lrec[i] = 0;
    __syncthreads();
    // place records
    for (int i = tid; i < cnt; i += 256) {
        u64 r = sb[i];
        int n = (int)(r >> 32) & 255;
        int p = atomicAdd(&lcur[n], 1);
        lrec[p] = (uint)r;
    }
    __syncthreads();
    // coalesced dump
    for (int i = tid; i < ptot; i += 256) recs[fbase + i] = lrec[i];
}

// ============ standalone gather: aggb[n] = sum w_e * featb[src_e] ============
// one wave per node; lane owns 2 bf16; ranges padded to x8 -> uniform 8-wide loop.
// No LDS, no barriers, lean VGPR -> high resident-wave count for latency hiding.
__global__ __launch_bounds__(256) void gather_k(const ushort* __restrict__ featb,
        const int2* __restrict__ rng, const uint* __restrict__ recs,
        ushort* __restrict__ aggb) {
    int node = blockIdx.x * 4 + (threadIdx.x >> 6);
    int lane2 = (threadIdx.x & 63) * 2;
    int2 r = rng[node];
    float a0 = 0.f, a1 = 0.f;
    for (int p = r.x; p < r.y; p += 8) {
        uint4 ra = *reinterpret_cast<const uint4*>(recs + p);
        uint4 rb = *reinterpret_cast<const uint4*>(recs + p + 4);
        uint u0 = *reinterpret_cast<const uint*>(featb + (size_t)(ra.x & 0xffffu) * F + lane2);
        uint u1 = *reinterpret_cast<const uint*>(featb + (size_t)(ra.y & 0xffffu) * F + lane2);
        uint u2 = *reinterpret_cast<const uint*>(featb + (size_t)(ra.z & 0xffffu) * F + lane2);
        uint u3 = *reinterpret_cast<const uint*>(featb + (size_t)(ra.w & 0xffffu) * F + lane2);
        uint u4 = *reinterpret_cast<const uint*>(featb + (size_t)(rb.x & 0xffffu) * F + lane2);
        uint u5 = *reinterpret_cast<const uint*>(featb + (size_t)(rb.y & 0xffffu) * F + lane2);
        uint u6 = *reinterpret_cast<const uint*>(featb + (size_t)(rb.z & 0xffffu) * F + lane2);
        uint u7 = *reinterpret_cast<const uint*>(featb + (size_t)(rb.w & 0xffffu) * F + lane2);
        float w0 = bf2f((ushort)(ra.x >> 16)), w1 = bf2f((ushort)(ra.y >> 16));
        float w2 = bf2f((ushort)(ra.z >> 16)), w3 = bf2f((ushort)(ra.w >> 16));
        float w4 = bf2f((ushort)(rb.x >> 16)), w5 = bf2f((ushort)(rb.y >> 16));
        float w6 = bf2f((ushort)(rb.z >> 16)), w7 = bf2f((ushort)(rb.w >> 16));
        a0 += w0 * bf2f((ushort)u0) + w1 * bf2f((ushort)u1)
            + w2 * bf2f((ushort)u2) + w3 * bf2f((ushort)u3)
            + w4 * bf2f((ushort)u4) + w5 * bf2f((ushort)u5)
            + w6 * bf2f((ushort)u6) + w7 * bf2f((ushort)u7);
        a1 += w0 * bf2f((ushort)(u0 >> 16)) + w1 * bf2f((ushort)(u1 >> 16))
            + w2 * bf2f((ushort)(u2 >> 16)) + w3 * bf2f((ushort)(u3 >> 16))
            + w4 * bf2f((ushort)(u4 >> 16)) + w5 * bf2f((ushort)(u5 >> 16))
            + w6 * bf2f((ushort)(u6 >> 16)) + w7 * bf2f((ushort)(u7 >> 16));
    }
    *reinterpret_cast<uint*>(aggb + (size_t)node * F + lane2) =
        (uint)f2bf(a0) | ((uint)f2bf(a1) << 16);
}

// ============ MFMA dual GEMM (W in registers, A direct from global) ============
// fuse_bn=1: write bf16 h to outh + accumulate BN stats. fuse_bn=0: write fp32 to out.
__global__ __launch_bounds__(256) void gemm_mfma(const ushort* __restrict__ R,
        const ushort* __restrict__ T, const ushort* __restrict__ Wr,
        const ushort* __restrict__ Wt, const float* __restrict__ bias,
        float* __restrict__ out, ushort* __restrict__ outh,
        float* __restrict__ S, float* __restrict__ S2, int fuse_bn) {
    const int lane = threadIdx.x & 63;
    const int wave = threadIdx.x >> 6;
    const int quad = lane >> 4;
    const int l16 = lane & 15;
    const int cb = wave * 32;

    bf16x8 bR[2][4], bT[2][4];
#pragma unroll
    for (int t = 0; t < 2; ++t)
#pragma unroll
        for (int s = 0; s < 4; ++s) {
            int col = cb + t * 16 + l16;
            int k0 = s * 32 + quad * 8;
            bR[t][s] = *reinterpret_cast<const bf16x8*>(Wr + col * F + k0);
            bT[t][s] = *reinterpret_cast<const bf16x8*>(Wt + col * F + k0);
        }
    const float bias0 = bias[cb + l16];
    const float bias1 = bias[cb + 16 + l16];

    float s0 = 0.f, q0 = 0.f, s1 = 0.f, q1 = 0.f;

    for (int rt = blockIdx.x; rt < N_RT; rt += GEMM_GRID) {
        const int row0 = rt * 16;
        const ushort* rA = R + (row0 + l16) * F + quad * 8;
        const ushort* tA = T + (row0 + l16) * F + quad * 8;
        bf16x8 aR0 = *reinterpret_cast<const bf16x8*>(rA);
        bf16x8 aR1 = *reinterpret_cast<const bf16x8*>(rA + 32);
        bf16x8 aR2 = *reinterpret_cast<const bf16x8*>(rA + 64);
        bf16x8 aR3 = *reinterpret_cast<const bf16x8*>(rA + 96);
        bf16x8 aT0 = *reinterpret_cast<const bf16x8*>(tA);
        bf16x8 aT1 = *reinterpret_cast<const bf16x8*>(tA + 32);
        bf16x8 aT2 = *reinterpret_cast<const bf16x8*>(tA + 64);
        bf16x8 aT3 = *reinterpret_cast<const bf16x8*>(tA + 96);

        f32x4 acc0 = {0.f, 0.f, 0.f, 0.f};
        f32x4 acc1 = {0.f, 0.f, 0.f, 0.f};
        acc0 = __builtin_amdgcn_mfma_f32_16x16x32_bf16(aR0, bR[0][0], acc0, 0, 0, 0);
        acc1 = __builtin_amdgcn_mfma_f32_16x16x32_bf16(aR0, bR[1][0], acc1, 0, 0, 0);
        acc0 = __builtin_amdgcn_mfma_f32_16x16x32_bf16(aR1, bR[0][1], acc0, 0, 0, 0);
        acc1 = __builtin_amdgcn_mfma_f32_16x16x32_bf16(aR1, bR[1][1], acc1, 0, 0, 0);
        acc0 = __builtin_amdgcn_mfma_f32_16x16x32_bf16(aR2, bR[0][2], acc0, 0, 0, 0);
        acc1 = __builtin_amdgcn_mfma_f32_16x16x32_bf16(aR2, bR[1][2], acc1, 0, 0, 0);
        acc0 = __builtin_amdgcn_mfma_f32_16x16x32_bf16(aR3, bR[0][3], acc0, 0, 0, 0);
        acc1 = __builtin_amdgcn_mfma_f32_16x16x32_bf16(aR3, bR[1][3], acc1, 0, 0, 0);
        acc0 = __builtin_amdgcn_mfma_f32_16x16x32_bf16(aT0, bT[0][0], acc0, 0, 0, 0);
        acc1 = __builtin_amdgcn_mfma_f32_16x16x32_bf16(aT0, bT[1][0], acc1, 0, 0, 0);
        acc0 = __builtin_amdgcn_mfma_f32_16x16x32_bf16(aT1, bT[0][1], acc0, 0, 0, 0);
        acc1 = __builtin_amdgcn_mfma_f32_16x16x32_bf16(aT1, bT[1][1], acc1, 0, 0, 0);
        acc0 = __builtin_amdgcn_mfma_f32_16x16x32_bf16(aT2, bT[0][2], acc0, 0, 0, 0);
        acc1 = __builtin_amdgcn_mfma_f32_16x16x32_bf16(aT2, bT[1][2], acc1, 0, 0, 0);
        acc0 = __builtin_amdgcn_mfma_f32_16x16x32_bf16(aT3, bT[0][3], acc0, 0, 0, 0);
        acc1 = __builtin_amdgcn_mfma_f32_16x16x32_bf16(aT3, bT[1][3], acc1, 0, 0, 0);

        const int r0 = row0 + quad * 4;  // C layout: col=lane&15, row=quad*4+reg
        if (fuse_bn) {
#pragma unroll
            for (int g = 0; g < 4; ++g) {
                float v0 = acc0[g] + bias0;
                float v1 = acc1[g] + bias1;
                outh[(r0 + g) * F + cb + l16] = f2bf(v0);
                outh[(r0 + g) * F + cb + 16 + l16] = f2bf(v1);
                s0 += v0; q0 += v0 * v0;
                s1 += v1; q1 += v1 * v1;
            }
        } else {
#pragma unroll
            for (int g = 0; g < 4; ++g) {
                out[(r0 + g) * F + cb + l16] = acc0[g] + bias0;
                out[(r0 + g) * F + cb + 16 + l16] = acc1[g] + bias1;
            }
        }
    }

    if (fuse_bn) {
        s0 += __shfl_down(s0, 32); s0 += __shfl_down(s0, 16);
        q0 += __shfl_down(q0, 32); q0 += __shfl_down(q0, 16);
        s1 += __shfl_down(s1, 32); s1 += __shfl_down(s1, 16);
        q1 += __shfl_down(q1, 32); q1 += __shfl_down(q1, 16);
        if (lane < 16) {
            unsafeAtomicAdd(&S[cb + lane], s0);
            unsafeAtomicAdd(&S2[cb + lane], q0);
            unsafeAtomicAdd(&S[cb + 16 + lane], s1);
            unsafeAtomicAdd(&S2[cb + 16 + lane], q1);
        }
    }
}

// ============ BN finalize (inline) + RReLU: hraw (bf16) -> hb (bf16) ============
__global__ __launch_bounds__(256) void norm_act_k(const ushort* __restrict__ hraw,
        const float* __restrict__ S, const float* __restrict__ S2,
        const float* __restrict__ gamma, const float* __restrict__ beta,
        ushort* __restrict__ hb) {
    __shared__ float sc_s[128], sh_s[128];
    if (threadIdx.x < 128) {
        int j = threadIdx.x;
        float mean = S[j] * (1.f / N_NODES);
        float var = S2[j] * (1.f / N_NODES) - mean * mean;
        float inv = rsqrtf(var + BN_EPS);
        float sc = gamma[j] * inv;
        sc_s[j] = sc;
        sh_s[j] = beta[j] - mean * sc;
    }
    __syncthreads();
    int i = blockIdx.x * 256 + threadIdx.x;  // 4 bf16 per thread
    int cbase = (i & 31) * 4;
    uint2 u = reinterpret_cast<const uint2*>(hraw)[i];
    float4 v = make_float4(bf2f((ushort)u.x), bf2f((ushort)(u.x >> 16)),
                           bf2f((ushort)u.y), bf2f((ushort)(u.y >> 16)));
    float4 sc = *reinterpret_cast<const float4*>(&sc_s[cbase]);
    float4 sh = *reinterpret_cast<const float4*>(&sh_s[cbase]);
    v.x = v.x * sc.x + sh.x;
    v.y = v.y * sc.y + sh.y;
    v.z = v.z * sc.z + sh.z;
    v.w = v.w * sc.w + sh.w;
    v.x = v.x >= 0.f ? v.x : v.x * SLOPE;
    v.y = v.y >= 0.f ? v.y : v.y * SLOPE;
    v.z = v.z >= 0.f ? v.z : v.z * SLOPE;
    v.w = v.w >= 0.f ? v.w : v.w * SLOPE;
    uint2 o;
    o.x = (uint)f2bf(v.x) | ((uint)f2bf(v.y) << 16);
    o.y = (uint)f2bf(v.z) | ((uint)f2bf(v.w) << 16);
    reinterpret_cast<uint2*>(hb)[i] = o;
}

extern "C" void kernel_launch(void* const* d_in, const int* in_sizes, int n_in,
                              void* d_out, int out_size, void* d_ws, size_t ws_size,
                              hipStream_t stream) {
    const float* x     = (const float*)d_in[0];
    const int*   ei    = (const int*)d_in[1];
    const float* ea    = (const float*)d_in[2];
    const float* W1r   = (const float*)d_in[3];
    const float* b1    = (const float*)d_in[4];
    const float* W1t   = (const float*)d_in[5];
    const float* gamma = (const float*)d_in[6];
    const float* beta  = (const float*)d_in[7];
    const float* W2r   = (const float*)d_in[8];
    const float* b2    = (const float*)d_in[9];
    const float* W2t   = (const float*)d_in[10];
    float* out = (float*)d_out;

    char* ws = (char*)d_ws;
    size_t off = 0;
    u64*    stg   = (u64*)(ws + off);    off += (size_t)NBKT * BKT_CAP * 8;  // 12.85 MB
    ushort* featb = (ushort*)(ws + off); off += (size_t)N_NODES * F * 2;     // 12.8 MB (xb -> hb)
    uint*   recs  = (uint*)(ws + off);   off += (size_t)REC_CAP * 4;         // 4.6 MB (no memset)
    int*    bcur  = (int*)(ws + off);    off += 256 * 4;                     // memset 0
    float*  S     = (float*)(ws + off);  off += 128 * 4;                     // memset 0
    float*  S2    = (float*)(ws + off);  off += 128 * 4;                     // memset 0
    int2*   rng   = (int2*)(ws + off);   off += (size_t)N_NODES * 8;         // 400 KB
    ushort* wb    = (ushort*)(ws + off); off += 4 * 16384 * 2;               // 128 KB
    ushort* aggb  = (ushort*)stg;        // aliases stg (dead after sort2); 12.8 MB
    ushort* hraw  = (ushort*)d_out;      // bf16 h in d_out storage (gemm2 overwrites)

    const int* srcp = ei;
    const int* tgtp = ei + N_EDGES;

    // tiny memset: bcur (cursors) + S/S2 (stats accum)
    hipMemsetAsync(bcur, 0, 256 * 4 + 256 * 4, stream);
    s1p_k<<<P1_BLKS + CASTX_BLKS + CASTW_BLKS, 256, 0, stream>>>(
        srcp, tgtp, ea, bcur, stg, x, featb, W1r, W1t, W2r, W2t, wb);
    sort2_k<<<NBKT, 256, 0, stream>>>(bcur, stg, recs, rng);

    // ---- layer 1: gather -> GEMM (+BN stats), bf16 h into d_out storage ----
    gather_k<<<N_NODES / 4, 256, 0, stream>>>(featb, rng, recs, aggb);
    gemm_mfma<<<GEMM_GRID, 256, 0, stream>>>(aggb, featb, wb, wb + 16384, b1,
                                             out, hraw, S, S2, 1);
    norm_act_k<<<CASTX_BLKS, 256, 0, stream>>>(hraw, S, S2, gamma, beta, featb);
    // ---- layer 2: gather -> GEMM, fp32 out ----
    gather_k<<<N_NODES / 4, 256, 0, stream>>>(featb, rng, recs, aggb);
    gemm_mfma<<<GEMM_GRID, 256, 0, stream>>>(aggb, featb, wb + 32768, wb + 49152, b2,
                                             out, hraw, S, S2, 0);
}